// Round 3
// baseline (607.017 us; speedup 1.0000x reference)
//
#include <hip/hip_runtime.h>
#include <math.h>

#define BB 4
#define NN 2048
#define EE 2048

typedef __attribute__((ext_vector_type(8))) unsigned short ushort8;
typedef __attribute__((ext_vector_type(4))) float f32x4;

// ---------- helpers ----------
__device__ __forceinline__ unsigned short f2bf(float f) {
  unsigned int u = __float_as_uint(f);
  u = u + 0x7fffu + ((u >> 16) & 1u);   // RNE; inputs are finite
  return (unsigned short)(u >> 16);
}

__device__ __forceinline__ f32x4 mfma16(ushort8 a, ushort8 b, f32x4 c) {
  asm("v_mfma_f32_16x16x32_bf16 %0, %1, %2, %0" : "+v"(c) : "v"(a), "v"(b));
  return c;
}

__device__ __forceinline__ void gload16(const void* g, void* l) {
  __builtin_amdgcn_global_load_lds(
      (__attribute__((address_space(1))) void*)g,
      (__attribute__((address_space(3))) void*)l, 16, 0, 0);
}

#define BARRIER() do { asm volatile("" ::: "memory"); __builtin_amdgcn_s_barrier(); asm volatile("" ::: "memory"); } while (0)

// ---------- fp32 -> bf16 conversion (vectorized) ----------
__global__ __launch_bounds__(256) void k_f32_to_bf16(const float* __restrict__ in,
                                                     unsigned short* __restrict__ out) {
  size_t i = (size_t)blockIdx.x * 256 + threadIdx.x;   // 8 elems each
  const float4* ip = (const float4*)in;
  float4 a = ip[i * 2];
  float4 b = ip[i * 2 + 1];
  ushort8 o;
  o[0] = f2bf(a.x); o[1] = f2bf(a.y); o[2] = f2bf(a.z); o[3] = f2bf(a.w);
  o[4] = f2bf(b.x); o[5] = f2bf(b.y); o[6] = f2bf(b.z); o[7] = f2bf(b.w);
  *((ushort8*)out + i) = o;
}

// ---------- bf16 transpose [N,E] -> [E,N] per batch ----------
__global__ __launch_bounds__(256) void k_transpose(const unsigned short* __restrict__ in,
                                                   unsigned short* __restrict__ out) {
  __shared__ __attribute__((aligned(16))) unsigned short tile[64][72];
  const long z = blockIdx.z;
  const long eb = (long)blockIdx.x * 64;
  const long nb = (long)blockIdx.y * 64;
  const unsigned short* ip = in + z * (long)NN * EE;
  unsigned short* op = out + z * (long)NN * EE;
  const int t = threadIdx.x;
  const int r = t >> 3;
  const int c = (t & 7) * 8;

  ushort8 u0 = *(const ushort8*)(ip + (nb + r) * EE + eb + c);
  ushort8 u1 = *(const ushort8*)(ip + (nb + 32 + r) * EE + eb + c);
  *(ushort8*)&tile[r][c] = u0;
  *(ushort8*)&tile[r + 32][c] = u1;
  __syncthreads();
  ushort8 o0, o1;
#pragma unroll
  for (int j = 0; j < 8; j++) { o0[j] = tile[c + j][r]; o1[j] = tile[c + j][r + 32]; }
  *(ushort8*)(op + (eb + r) * NN + nb + c) = o0;
  *(ushort8*)(op + (eb + r + 32) * NN + nb + c) = o1;
}

// ---------- 256x256 8-wave 8-phase GEMM (m201 template): C[m,n] = sum_k A[m,k]*B[n,k] ----------
// EPI 0: bf16 out (+bias if non-null)   EPI 1: f32, acc*scale + mask*(-1e9)   EPI 2: f32 + bias
// LDS: A,B double-buffered; each buf = 2 halves of [128 rows][64 cols] bf16, row-major 128B rows.
// st_16x32 swizzle: phys_byte = logical_byte ^ ((row_bit2)<<5). Staging keeps LDS linear
// (global_load_lds) and inverse-swizzles the GLOBAL source column -> full 128B-line coalescing.
// Schedule: 2 K-tiles (BK=64) per iteration, 8 phases, 1 half-tile stage per phase,
// counted vmcnt(4) at P4/P8 only. K must be a multiple of 128.
template <int EPI>
__global__ __launch_bounds__(512, 2) void k_gemm256(
    const unsigned short* __restrict__ A, long lda, long sA,
    const unsigned short* __restrict__ Bm, long ldb, long sB,
    void* __restrict__ Cv, long ldc, long sC, int K,
    const float* __restrict__ bias,
    const int* __restrict__ mask, long sMask, float scale) {
  __shared__ __attribute__((aligned(16))) unsigned short As[2 * 16384];
  __shared__ __attribute__((aligned(16))) unsigned short Bs[2 * 16384];

  // bijective XCD-chunk swizzle (nwg is always a multiple of 8 here)
  const int gx = gridDim.x, gy = gridDim.y;
  int lin = (int)blockIdx.x + gx * ((int)blockIdx.y + gy * (int)blockIdx.z);
  int nwg = gx * gy * (int)gridDim.z;
  int chunk = nwg >> 3;
  int sw = (lin & 7) * chunk + (lin >> 3);
  int bz = sw / (gx * gy); int rem = sw - bz * (gx * gy);
  int by = rem / gx; int bx = rem - by * gx;

  const long m0 = (long)by * 256;
  const long n0 = (long)bx * 256;
  const unsigned short* Ab = A + (long)bz * sA;
  const unsigned short* Bb = Bm + (long)bz * sB;

  const int t = threadIdx.x;
  const int lane = t & 63;
  const int w = t >> 6;
  const int wm = w >> 2;          // 0..1 (M-warp -> A half)
  const int wn = w & 3;           // 0..3 (N-warp)

  // ---- staging: thread t covers 16B of a 128B row; col inverse-swizzled by row bit2 ----
  const int srow = t >> 3;                                          // 0..63 per call
  const int scol = (((t & 7) * 16) ^ (((t >> 5) & 1) << 5)) >> 1;   // elements
  const unsigned short* Ga = Ab + (m0 + srow) * lda + scol;
  const unsigned short* Gb = Bb + (n0 + srow) * ldb + scol;

#define STAGE_A(buf, h, tile) do { \
    const unsigned short* g_ = Ga + (long)(tile) * 64 + (long)(h) * 128 * lda; \
    unsigned short* l_ = As + (buf) * 16384 + (h) * 8192 + t * 8; \
    gload16(g_, l_); gload16(g_ + 64 * lda, l_ + 4096); \
  } while (0)
#define STAGE_B(buf, h, tile) do { \
    const unsigned short* g_ = Gb + (long)(tile) * 64 + (long)(h) * 128 * ldb; \
    unsigned short* l_ = Bs + (buf) * 16384 + (h) * 8192 + t * 8; \
    gload16(g_, l_); gload16(g_ + 64 * ldb, l_ + 4096); \
  } while (0)

  // ---- read-side lane constants (swizzled ds_read addresses, element units) ----
  const int r = lane & 15;
  const int q = lane >> 4;
  const int rb = (r * 128 + q * 16) ^ ((r & 4) << 3);   // byte offset before mi/kk/half
  const int aBase = wm * 8192 + (rb >> 1);                          // + mi*1024 + kk*32
  const int bBase = (wn >> 1) * 8192 + (wn & 1) * 4096 + (rb >> 1); // + ni*1024 + kk*32

#define RD_A(bp, mbase) do { \
    _Pragma("unroll") for (int mi = 0; mi < 4; mi++) \
    _Pragma("unroll") for (int kk = 0; kk < 2; kk++) \
      a[mi][kk] = *(const ushort8*)((bp) + aBase + ((mbase) + mi) * 1024 + kk * 32); \
  } while (0)
#define RD_B(bp, nbase) do { \
    _Pragma("unroll") for (int ni = 0; ni < 2; ni++) \
    _Pragma("unroll") for (int kk = 0; kk < 2; kk++) \
      b[(nbase) + ni][kk] = *(const ushort8*)((bp) + bBase + ((nbase) + ni) * 1024 + kk * 32); \
  } while (0)
#define MFMA_Q(mbase, nbase) do { \
    BARRIER(); \
    __builtin_amdgcn_s_setprio(1); \
    _Pragma("unroll") for (int mi = 0; mi < 4; mi++) \
    _Pragma("unroll") for (int ni = 0; ni < 2; ni++) \
    _Pragma("unroll") for (int kk = 0; kk < 2; kk++) \
      acc[(mbase) + mi][(nbase) + ni] = \
          mfma16(a[mi][kk], b[(nbase) + ni][kk], acc[(mbase) + mi][(nbase) + ni]); \
    __builtin_amdgcn_s_setprio(0); \
    BARRIER(); \
  } while (0)

  f32x4 acc[8][4] = {};
  ushort8 a[4][2], b[4][2];
  const unsigned short* A0 = As;
  const unsigned short* B0 = Bs;
  const unsigned short* A1 = As + 16384;
  const unsigned short* B1 = Bs + 16384;
  const int J = K >> 7;   // iterations, 2 K-tiles each

  // ---- prologue: tile0 fully, B(tile1); A(tile1) staged in P1/P2 of iter 0 ----
  STAGE_B(0, 0, 0); STAGE_B(0, 1, 0);
  STAGE_A(0, 0, 0); STAGE_A(0, 1, 0);
  STAGE_B(1, 0, 1); STAGE_B(1, 1, 1);
  asm volatile("s_waitcnt vmcnt(4)" ::: "memory");   // tile0 resident; B(1) in flight
  BARRIER();

  for (int j = 0; j < J; ++j) {
    const int t0 = 2 * j, t1 = 2 * j + 1;
    const bool pf = (j + 1 < J);

    // ---- K-tile t0 (buf0) ----
    RD_A(A0, 0); RD_B(B0, 0);          // P1: a0-3, b0-1 (12 reads)
    STAGE_A(1, 0, t1);                 // A(t1) h0 -> buf1 (dead since P7 of j-1)
    MFMA_Q(0, 0);

    RD_B(B0, 2);                       // P2: b2-3
    STAGE_A(1, 1, t1);
    MFMA_Q(0, 2);

    RD_A(A0, 4);                       // P3: a4-7
    if (pf) STAGE_B(0, 0, t0 + 2);     // B-buf0 dead after P2
    MFMA_Q(4, 0);

    if (pf) {                          // P4
      STAGE_B(0, 1, t0 + 2);
      asm volatile("s_waitcnt vmcnt(4)" ::: "memory");   // tile t1 resident
    } else {
      asm volatile("s_waitcnt vmcnt(0)" ::: "memory");
    }
    MFMA_Q(4, 2);

    // ---- K-tile t1 (buf1) ----
    RD_A(A1, 0); RD_B(B1, 0);          // P5
    if (pf) STAGE_A(0, 0, t0 + 2);     // A-buf0 dead after P3
    MFMA_Q(0, 0);

    RD_B(B1, 2);                       // P6
    if (pf) STAGE_A(0, 1, t0 + 2);
    MFMA_Q(0, 2);

    RD_A(A1, 4);                       // P7
    if (pf) STAGE_B(1, 0, t1 + 2);     // B-buf1 dead after P6
    MFMA_Q(4, 0);

    if (pf) {                          // P8
      STAGE_B(1, 1, t1 + 2);
      asm volatile("s_waitcnt vmcnt(4)" ::: "memory");   // tile t0+2 resident
    }
    MFMA_Q(4, 2);
  }
#undef STAGE_A
#undef STAGE_B
#undef RD_A
#undef RD_B
#undef MFMA_Q

  // ---- epilogue: C/D mapping col=lane&15, row=(lane>>4)*4+reg ----
  const int cr0 = wm * 128 + (q << 2);
  const int cc0 = wn * 64 + r;
  if (EPI == 0) {
    unsigned short* Co = (unsigned short*)Cv + (long)bz * sC;
#pragma unroll
    for (int mi = 0; mi < 8; mi++)
#pragma unroll
      for (int rr = 0; rr < 4; rr++) {
        long row = m0 + cr0 + mi * 16 + rr;
#pragma unroll
        for (int ni = 0; ni < 4; ni++) {
          long col = n0 + cc0 + ni * 16;
          float v = acc[mi][ni][rr];
          if (bias) v += bias[col];
          Co[row * ldc + col] = f2bf(v);
        }
      }
  } else if (EPI == 1) {
    float* Co = (float*)Cv + (long)bz * sC;
    const int* Mp = mask + (long)bz * sMask;
#pragma unroll
    for (int mi = 0; mi < 8; mi++)
#pragma unroll
      for (int rr = 0; rr < 4; rr++) {
        long row = m0 + cr0 + mi * 16 + rr;
#pragma unroll
        for (int ni = 0; ni < 4; ni++) {
          long col = n0 + cc0 + ni * 16;
          Co[row * ldc + col] = acc[mi][ni][rr] * scale + (float)Mp[row * ldc + col] * -1e9f;
        }
      }
  } else {
    float* Co = (float*)Cv + (long)bz * sC;
#pragma unroll
    for (int mi = 0; mi < 8; mi++)
#pragma unroll
      for (int rr = 0; rr < 4; rr++) {
        long row = m0 + cr0 + mi * 16 + rr;
#pragma unroll
        for (int ni = 0; ni < 4; ni++) {
          long col = n0 + cc0 + ni * 16;
          Co[row * ldc + col] = acc[mi][ni][rr] + bias[col];
        }
      }
  }
}

// ---------- edge gate + softmax, one row per block; writes bf16 attn in place ----------
__global__ __launch_bounds__(256) void k_edge_softmax(float* __restrict__ scores,
                                                      const float* __restrict__ We,
                                                      const float* __restrict__ be) {
  __shared__ float r1[4], r2[4], r3[4];
  const long row = blockIdx.x;
  float* srow = scores + row * (long)NN;
  const int t = threadIdx.x;
  const int lane = t & 63;
  const int w = t >> 6;

  float4 a = *(const float4*)(srow + t * 8);
  float4 b = *(const float4*)(srow + t * 8 + 4);
  float s[8] = {a.x, a.y, a.z, a.w, b.x, b.y, b.z, b.w};
  float4 wa = *(const float4*)(We + t * 8);
  float4 wb = *(const float4*)(We + t * 8 + 4);
  float wv[8] = {wa.x, wa.y, wa.z, wa.w, wb.x, wb.y, wb.z, wb.w};

  float dot = 0.f;
#pragma unroll
  for (int j = 0; j < 8; j++) dot += s[j] * wv[j];
#pragma unroll
  for (int off = 32; off >= 1; off >>= 1) dot += __shfl_down(dot, off);
  if (lane == 0) r1[w] = dot;
  __syncthreads();
  float edot = r1[0] + r1[1] + r1[2] + r1[3] + be[0];
  float edge = 1.0f / (1.0f + expf(-edot));

  float mx = -3.4e38f;
#pragma unroll
  for (int j = 0; j < 8; j++) { s[j] *= edge; mx = fmaxf(mx, s[j]); }
#pragma unroll
  for (int off = 32; off >= 1; off >>= 1) mx = fmaxf(mx, __shfl_down(mx, off));
  if (lane == 0) r2[w] = mx;
  __syncthreads();
  mx = fmaxf(fmaxf(r2[0], r2[1]), fmaxf(r2[2], r2[3]));

  float sum = 0.f;
  float p[8];
#pragma unroll
  for (int j = 0; j < 8; j++) { p[j] = expf(s[j] - mx); sum += p[j]; }
#pragma unroll
  for (int off = 32; off >= 1; off >>= 1) sum += __shfl_down(sum, off);
  if (lane == 0) r3[w] = sum;
  __syncthreads();
  sum = r3[0] + r3[1] + r3[2] + r3[3];
  float inv = 1.0f / sum;

  ushort8 o;
#pragma unroll
  for (int j = 0; j < 8; j++) o[j] = f2bf(p[j] * inv);
  *(ushort8*)((unsigned short*)srow + t * 8) = o;
}

// ---------- launch ----------
extern "C" void kernel_launch(void* const* d_in, const int* in_sizes, int n_in,
                              void* d_out, int out_size, void* d_ws, size_t ws_size,
                              hipStream_t stream) {
  (void)in_sizes; (void)n_in; (void)out_size; (void)ws_size;
  const float* query = (const float*)d_in[0];
  const float* key_  = (const float*)d_in[1];
  const float* value = (const float*)d_in[2];
  const int*   mask  = (const int*)d_in[3];
  const float* Wq = (const float*)d_in[4];
  const float* bq = (const float*)d_in[5];
  const float* Wk = (const float*)d_in[6];
  const float* bk = (const float*)d_in[7];
  const float* Wv = (const float*)d_in[8];
  const float* bv = (const float*)d_in[9];
  const float* We = (const float*)d_in[10];
  const float* be = (const float*)d_in[11];
  const float* Wo = (const float*)d_in[12];
  const float* bo = (const float*)d_in[13];
  float* out = (float*)d_out;

  const long NE = (long)BB * NN * EE;
  const size_t SZ = (size_t)NE * 2;
  char* ws = (char*)d_ws;
  unsigned short* X  = (unsigned short*)(ws);           // conv buffer, later Vt
  unsigned short* Qb = (unsigned short*)(ws + SZ);
  unsigned short* Kb = (unsigned short*)(ws + 2 * SZ);
  unsigned short* Vb = (unsigned short*)(ws + 3 * SZ);  // later O
  unsigned short* Wb = (unsigned short*)(ws + 4 * SZ);  // 4 x E*E bf16
  float* SC = (float*)(ws + 5 * SZ);                    // scores fp32; attn bf16 in place

  const float scale = 1.0f / sqrtf((float)EE);
  dim3 blk(256), blk5(512);
  const long WE2 = (long)EE * EE;

  // weights -> bf16
  k_f32_to_bf16<<<2048, blk, 0, stream>>>(Wq, Wb + 0 * WE2);
  k_f32_to_bf16<<<2048, blk, 0, stream>>>(Wk, Wb + 1 * WE2);
  k_f32_to_bf16<<<2048, blk, 0, stream>>>(Wv, Wb + 2 * WE2);
  k_f32_to_bf16<<<2048, blk, 0, stream>>>(Wo, Wb + 3 * WE2);

  // projections (M = B*N = 8192)
  k_f32_to_bf16<<<8192, blk, 0, stream>>>(query, X);
  k_gemm256<0><<<dim3(8, 32, 1), blk5, 0, stream>>>(X, EE, 0, Wb + 0 * WE2, EE, 0,
      Qb, EE, 0, EE, bq, nullptr, 0, 0.f);
  k_f32_to_bf16<<<8192, blk, 0, stream>>>(key_, X);
  k_gemm256<0><<<dim3(8, 32, 1), blk5, 0, stream>>>(X, EE, 0, Wb + 1 * WE2, EE, 0,
      Kb, EE, 0, EE, bk, nullptr, 0, 0.f);
  k_f32_to_bf16<<<8192, blk, 0, stream>>>(value, X);
  k_gemm256<0><<<dim3(8, 32, 1), blk5, 0, stream>>>(X, EE, 0, Wb + 2 * WE2, EE, 0,
      Vb, EE, 0, EE, bv, nullptr, 0, 0.f);

  // Vt[e,n] = V[n,e]
  k_transpose<<<dim3(32, 32, BB), blk, 0, stream>>>(Vb, X);

  // scores = Q K^T * scale + mask*(-1e9)   [fp32]
  k_gemm256<1><<<dim3(8, 8, BB), blk5, 0, stream>>>(Qb, EE, (long)NN * EE, Kb, EE, (long)NN * EE,
      SC, NN, (long)NN * NN, EE, nullptr, mask, (long)NN * NN, scale);

  // edge gate + softmax -> bf16 attn in place (row stride 2N bf16 elements)
  k_edge_softmax<<<BB * NN, blk, 0, stream>>>(SC, We, be);

  // O = attn * Vt^T  -> Vb region (bf16)
  k_gemm256<0><<<dim3(8, 8, BB), blk5, 0, stream>>>((const unsigned short*)SC, 2 * NN,
      (long)NN * 2 * NN, X, NN, (long)EE * NN, Vb, EE, (long)NN * EE, NN,
      nullptr, nullptr, 0, 0.f);

  // out = O * Wo^T + bo   [fp32]
  k_gemm256<2><<<dim3(8, 32, 1), blk5, 0, stream>>>(Vb, EE, 0, Wb + 3 * WE2, EE, 0,
      out, EE, 0, EE, bo, nullptr, 0, 0.f);
}

// Round 4
// 570.436 us; speedup vs baseline: 1.0641x; 1.0641x over previous
//
#include <hip/hip_runtime.h>
#include <math.h>

#define BB 4
#define NN 2048
#define EE 2048

typedef __attribute__((ext_vector_type(8))) unsigned short ushort8;
typedef __attribute__((ext_vector_type(8))) __bf16 bf16x8;
typedef __attribute__((ext_vector_type(4))) float f32x4;

// ---------- helpers ----------
__device__ __forceinline__ unsigned short f2bf(float f) {
  unsigned int u = __float_as_uint(f);
  u = u + 0x7fffu + ((u >> 16) & 1u);   // RNE; inputs are finite
  return (unsigned short)(u >> 16);
}

__device__ __forceinline__ void gload16(const void* g, void* l) {
  __builtin_amdgcn_global_load_lds(
      (__attribute__((address_space(1))) void*)g,
      (__attribute__((address_space(3))) void*)l, 16, 0, 0);
}

#define BARRIER() do { asm volatile("" ::: "memory"); __builtin_amdgcn_s_barrier(); asm volatile("" ::: "memory"); } while (0)

// ---------- fp32 -> bf16 conversion (vectorized) ----------
__global__ __launch_bounds__(256) void k_f32_to_bf16(const float* __restrict__ in,
                                                     unsigned short* __restrict__ out) {
  size_t i = (size_t)blockIdx.x * 256 + threadIdx.x;   // 8 elems each
  const float4* ip = (const float4*)in;
  float4 a = ip[i * 2];
  float4 b = ip[i * 2 + 1];
  ushort8 o;
  o[0] = f2bf(a.x); o[1] = f2bf(a.y); o[2] = f2bf(a.z); o[3] = f2bf(a.w);
  o[4] = f2bf(b.x); o[5] = f2bf(b.y); o[6] = f2bf(b.z); o[7] = f2bf(b.w);
  *((ushort8*)out + i) = o;
}

// ---------- bf16 transpose [N,E] -> [E,N] per batch ----------
__global__ __launch_bounds__(256) void k_transpose(const unsigned short* __restrict__ in,
                                                   unsigned short* __restrict__ out) {
  __shared__ __attribute__((aligned(16))) unsigned short tile[64][72];
  const long z = blockIdx.z;
  const long eb = (long)blockIdx.x * 64;
  const long nb = (long)blockIdx.y * 64;
  const unsigned short* ip = in + z * (long)NN * EE;
  unsigned short* op = out + z * (long)NN * EE;
  const int t = threadIdx.x;
  const int r = t >> 3;
  const int c = (t & 7) * 8;

  ushort8 u0 = *(const ushort8*)(ip + (nb + r) * EE + eb + c);
  ushort8 u1 = *(const ushort8*)(ip + (nb + 32 + r) * EE + eb + c);
  *(ushort8*)&tile[r][c] = u0;
  *(ushort8*)&tile[r + 32][c] = u1;
  __syncthreads();
  ushort8 o0, o1;
#pragma unroll
  for (int j = 0; j < 8; j++) { o0[j] = tile[c + j][r]; o1[j] = tile[c + j][r + 32]; }
  *(ushort8*)(op + (eb + r) * NN + nb + c) = o0;
  *(ushort8*)(op + (eb + r + 32) * NN + nb + c) = o1;
}

// ---------- 256x256 8-wave 8-phase GEMM: C[m,n] = sum_k A[m,k]*B[n,k] ----------
// EPI 0: bf16 out (+bias if non-null)   EPI 1: f32, acc*scale + mask*(-1e9)   EPI 2: f32 + bias
// LDS logical layout per 128x64 half: [8 rowgroups(16r)][2 khalves(32c)][16 rows][32 cols] bf16,
// phys_byte = logical_byte ^ (bit3(row_lo)<<5)  (R2 layout: measured 0 bank conflicts).
// Staging stays LDS-linear (global_load_lds, dest=t*16B) with the inverse swizzle folded into
// the GLOBAL source address. MFMA via builtin so accumulators live in AGPRs (no accvgpr shuttling).
// Schedule: 2 K-tiles (BK=64)/iter, 8 phases, 1 half-tile stage/phase, counted vmcnt(4) at P4/P8.
template <int EPI>
__global__ __launch_bounds__(512, 2) void k_gemm256(
    const unsigned short* __restrict__ A, long lda, long sA,
    const unsigned short* __restrict__ Bm, long ldb, long sB,
    void* __restrict__ Cv, long ldc, long sC, int K,
    const float* __restrict__ bias,
    const int* __restrict__ mask, long sMask, float scale) {
  __shared__ __attribute__((aligned(16))) unsigned short As[2 * 16384];
  __shared__ __attribute__((aligned(16))) unsigned short Bs[2 * 16384];

  // bijective XCD-chunk swizzle (nwg is always a multiple of 8 here)
  const int gx = gridDim.x, gy = gridDim.y;
  int lin = (int)blockIdx.x + gx * ((int)blockIdx.y + gy * (int)blockIdx.z);
  int nwg = gx * gy * (int)gridDim.z;
  int chunk = nwg >> 3;
  int sw = (lin & 7) * chunk + (lin >> 3);
  int bz = sw / (gx * gy); int rem = sw - bz * (gx * gy);
  int by = rem / gx; int bx = rem - by * gx;

  const long m0 = (long)by * 256;
  const long n0 = (long)bx * 256;
  const unsigned short* Ab = A + (long)bz * sA;
  const unsigned short* Bb = Bm + (long)bz * sB;

  const int t = threadIdx.x;
  const int lane = t & 63;
  const int w = t >> 6;
  const int wm = w >> 2;          // 0..1 (M-warp -> A half)
  const int wn = w & 3;           // 0..3 (N-warp)

  // ---- staging: LDS dest byte p0 = t*16 (linear); logical q0 = p0 ^ (bit9(p0)<<5) ----
  const int p0 = t * 16;
  const int q0 = p0 ^ (((p0 >> 9) & 1) << 5);
  const int srow = ((q0 >> 10) >> 1) * 16 + ((q0 >> 6) & 15);   // row in 64-row round
  const int scol = ((q0 >> 10) & 1) * 32 + ((q0 & 63) >> 1);    // col (elements)
  const unsigned short* Ga = Ab + (m0 + srow) * lda + scol;
  const unsigned short* Gb = Bb + (n0 + srow) * ldb + scol;
  const int ldst = t * 8;   // ushort index of round-0 dest

#define STAGE_A(buf, h, tile) do { \
    const unsigned short* g_ = Ga + (long)(tile) * 64 + (long)(h) * 128 * lda; \
    unsigned short* l_ = As + (buf) * 16384 + (h) * 8192 + ldst; \
    gload16(g_, l_); gload16(g_ + 64 * lda, l_ + 4096); \
  } while (0)
#define STAGE_B(buf, h, tile) do { \
    const unsigned short* g_ = Gb + (long)(tile) * 64 + (long)(h) * 128 * ldb; \
    unsigned short* l_ = Bs + (buf) * 16384 + (h) * 8192 + ldst; \
    gload16(g_, l_); gload16(g_ + 64 * ldb, l_ + 4096); \
  } while (0)

  // ---- read-side lane constants (element units, swizzled) ----
  const int r = lane & 15;
  const int q = lane >> 4;
  const int c2h = ((q * 16) ^ (((lane >> 3) & 1) << 5)) >> 1;
  const int aBase = wm * 8192 + r * 32 + c2h;                       // + mi*1024 + kk*512
  const int bBase = (wn >> 1) * 8192 + (wn & 1) * 4096 + r * 32 + c2h; // + ni*1024 + kk*512

#define RD_A(bp, mbase) do { \
    _Pragma("unroll") for (int mi = 0; mi < 4; mi++) \
    _Pragma("unroll") for (int kk = 0; kk < 2; kk++) \
      a[mi][kk] = *(const bf16x8*)((bp) + aBase + ((mbase) + mi) * 1024 + kk * 512); \
  } while (0)
#define RD_B(bp, nbase) do { \
    _Pragma("unroll") for (int ni = 0; ni < 2; ni++) \
    _Pragma("unroll") for (int kk = 0; kk < 2; kk++) \
      b[(nbase) + ni][kk] = *(const bf16x8*)((bp) + bBase + ((nbase) + ni) * 1024 + kk * 512); \
  } while (0)
#define MFMA_Q(mbase, nbase) do { \
    BARRIER(); \
    __builtin_amdgcn_s_setprio(1); \
    _Pragma("unroll") for (int mi = 0; mi < 4; mi++) \
    _Pragma("unroll") for (int ni = 0; ni < 2; ni++) \
    _Pragma("unroll") for (int kk = 0; kk < 2; kk++) \
      acc[(mbase) + mi][(nbase) + ni] = __builtin_amdgcn_mfma_f32_16x16x32_bf16( \
          a[mi][kk], b[(nbase) + ni][kk], acc[(mbase) + mi][(nbase) + ni], 0, 0, 0); \
    __builtin_amdgcn_s_setprio(0); \
    BARRIER(); \
  } while (0)

  f32x4 acc[8][4] = {};
  bf16x8 a[4][2], b[4][2];
  const unsigned short* A0 = As;
  const unsigned short* B0 = Bs;
  const unsigned short* A1 = As + 16384;
  const unsigned short* B1 = Bs + 16384;
  const int J = K >> 7;   // iterations, 2 K-tiles each

  // ---- prologue: tile0 fully, B(tile1); A(tile1) staged in P1/P2 of iter 0 ----
  STAGE_B(0, 0, 0); STAGE_B(0, 1, 0);
  STAGE_A(0, 0, 0); STAGE_A(0, 1, 0);
  STAGE_B(1, 0, 1); STAGE_B(1, 1, 1);
  asm volatile("s_waitcnt vmcnt(4)" ::: "memory");   // tile0 resident; B(1) in flight
  BARRIER();

  for (int j = 0; j < J; ++j) {
    const int t0 = 2 * j, t1 = 2 * j + 1;
    const bool pf = (j + 1 < J);

    // ---- K-tile t0 (buf0) ----
    RD_A(A0, 0); RD_B(B0, 0);          // P1: a0-3, b0-1 (12 reads)
    STAGE_A(1, 0, t1);                 // A-buf1 dead since P7 of j-1
    MFMA_Q(0, 0);

    RD_B(B0, 2);                       // P2: b2-3
    STAGE_A(1, 1, t1);
    MFMA_Q(0, 2);

    RD_A(A0, 4);                       // P3: a4-7
    if (pf) STAGE_B(0, 0, t0 + 2);     // B-buf0 dead after P2
    MFMA_Q(4, 0);

    if (pf) {                          // P4
      STAGE_B(0, 1, t0 + 2);
      asm volatile("s_waitcnt vmcnt(4)" ::: "memory");   // tile t1 resident
    } else {
      asm volatile("s_waitcnt vmcnt(0)" ::: "memory");
    }
    MFMA_Q(4, 2);

    // ---- K-tile t1 (buf1) ----
    RD_A(A1, 0); RD_B(B1, 0);          // P5
    if (pf) STAGE_A(0, 0, t0 + 2);     // A-buf0 dead after P3
    MFMA_Q(0, 0);

    RD_B(B1, 2);                       // P6
    if (pf) STAGE_A(0, 1, t0 + 2);
    MFMA_Q(0, 2);

    RD_A(A1, 4);                       // P7
    if (pf) STAGE_B(1, 0, t1 + 2);     // B-buf1 dead after P6
    MFMA_Q(4, 0);

    if (pf) {                          // P8
      STAGE_B(1, 1, t1 + 2);
      asm volatile("s_waitcnt vmcnt(4)" ::: "memory");   // tile t0+2 resident
    }
    MFMA_Q(4, 2);
  }
#undef STAGE_A
#undef STAGE_B
#undef RD_A
#undef RD_B
#undef MFMA_Q

  // ---- epilogue: C/D mapping col=lane&15, row=(lane>>4)*4+reg ----
  const int cr0 = wm * 128 + (q << 2);
  const int cc0 = wn * 64 + r;
  if (EPI == 0) {
    unsigned short* Co = (unsigned short*)Cv + (long)bz * sC;
#pragma unroll
    for (int mi = 0; mi < 8; mi++)
#pragma unroll
      for (int rr = 0; rr < 4; rr++) {
        long row = m0 + cr0 + mi * 16 + rr;
#pragma unroll
        for (int ni = 0; ni < 4; ni++) {
          long col = n0 + cc0 + ni * 16;
          float v = acc[mi][ni][rr];
          if (bias) v += bias[col];
          Co[row * ldc + col] = f2bf(v);
        }
      }
  } else if (EPI == 1) {
    float* Co = (float*)Cv + (long)bz * sC;
    const int* Mp = mask + (long)bz * sMask;
#pragma unroll
    for (int mi = 0; mi < 8; mi++)
#pragma unroll
      for (int rr = 0; rr < 4; rr++) {
        long row = m0 + cr0 + mi * 16 + rr;
#pragma unroll
        for (int ni = 0; ni < 4; ni++) {
          long col = n0 + cc0 + ni * 16;
          Co[row * ldc + col] = acc[mi][ni][rr] * scale + (float)Mp[row * ldc + col] * -1e9f;
        }
      }
  } else {
    float* Co = (float*)Cv + (long)bz * sC;
#pragma unroll
    for (int mi = 0; mi < 8; mi++)
#pragma unroll
      for (int rr = 0; rr < 4; rr++) {
        long row = m0 + cr0 + mi * 16 + rr;
#pragma unroll
        for (int ni = 0; ni < 4; ni++) {
          long col = n0 + cc0 + ni * 16;
          Co[row * ldc + col] = acc[mi][ni][rr] + bias[col];
        }
      }
  }
}

// ---------- edge gate + softmax, one row per block; writes bf16 attn in place ----------
__global__ __launch_bounds__(256) void k_edge_softmax(float* __restrict__ scores,
                                                      const float* __restrict__ We,
                                                      const float* __restrict__ be) {
  __shared__ float r1[4], r2[4], r3[4];
  const long row = blockIdx.x;
  float* srow = scores + row * (long)NN;
  const int t = threadIdx.x;
  const int lane = t & 63;
  const int w = t >> 6;

  float4 a = *(const float4*)(srow + t * 8);
  float4 b = *(const float4*)(srow + t * 8 + 4);
  float s[8] = {a.x, a.y, a.z, a.w, b.x, b.y, b.z, b.w};
  float4 wa = *(const float4*)(We + t * 8);
  float4 wb = *(const float4*)(We + t * 8 + 4);
  float wv[8] = {wa.x, wa.y, wa.z, wa.w, wb.x, wb.y, wb.z, wb.w};

  float dot = 0.f;
#pragma unroll
  for (int j = 0; j < 8; j++) dot += s[j] * wv[j];
#pragma unroll
  for (int off = 32; off >= 1; off >>= 1) dot += __shfl_down(dot, off);
  if (lane == 0) r1[w] = dot;
  __syncthreads();
  float edot = r1[0] + r1[1] + r1[2] + r1[3] + be[0];
  float edge = 1.0f / (1.0f + expf(-edot));

  float mx = -3.4e38f;
#pragma unroll
  for (int j = 0; j < 8; j++) { s[j] *= edge; mx = fmaxf(mx, s[j]); }
#pragma unroll
  for (int off = 32; off >= 1; off >>= 1) mx = fmaxf(mx, __shfl_down(mx, off));
  if (lane == 0) r2[w] = mx;
  __syncthreads();
  mx = fmaxf(fmaxf(r2[0], r2[1]), fmaxf(r2[2], r2[3]));

  float sum = 0.f;
  float p[8];
#pragma unroll
  for (int j = 0; j < 8; j++) { p[j] = expf(s[j] - mx); sum += p[j]; }
#pragma unroll
  for (int off = 32; off >= 1; off >>= 1) sum += __shfl_down(sum, off);
  if (lane == 0) r3[w] = sum;
  __syncthreads();
  sum = r3[0] + r3[1] + r3[2] + r3[3];
  float inv = 1.0f / sum;

  ushort8 o;
#pragma unroll
  for (int j = 0; j < 8; j++) o[j] = f2bf(p[j] * inv);
  *(ushort8*)((unsigned short*)srow + t * 8) = o;
}

// ---------- launch ----------
extern "C" void kernel_launch(void* const* d_in, const int* in_sizes, int n_in,
                              void* d_out, int out_size, void* d_ws, size_t ws_size,
                              hipStream_t stream) {
  (void)in_sizes; (void)n_in; (void)out_size; (void)ws_size;
  const float* query = (const float*)d_in[0];
  const float* key_  = (const float*)d_in[1];
  const float* value = (const float*)d_in[2];
  const int*   mask  = (const int*)d_in[3];
  const float* Wq = (const float*)d_in[4];
  const float* bq = (const float*)d_in[5];
  const float* Wk = (const float*)d_in[6];
  const float* bk = (const float*)d_in[7];
  const float* Wv = (const float*)d_in[8];
  const float* bv = (const float*)d_in[9];
  const float* We = (const float*)d_in[10];
  const float* be = (const float*)d_in[11];
  const float* Wo = (const float*)d_in[12];
  const float* bo = (const float*)d_in[13];
  float* out = (float*)d_out;

  const long NE = (long)BB * NN * EE;
  const size_t SZ = (size_t)NE * 2;
  char* ws = (char*)d_ws;
  unsigned short* X  = (unsigned short*)(ws);           // conv buffer, later Vt
  unsigned short* Qb = (unsigned short*)(ws + SZ);
  unsigned short* Kb = (unsigned short*)(ws + 2 * SZ);
  unsigned short* Vb = (unsigned short*)(ws + 3 * SZ);  // later O
  unsigned short* Wb = (unsigned short*)(ws + 4 * SZ);  // 4 x E*E bf16
  float* SC = (float*)(ws + 5 * SZ);                    // scores fp32; attn bf16 in place

  const float scale = 1.0f / sqrtf((float)EE);
  dim3 blk(256), blk5(512);
  const long WE2 = (long)EE * EE;

  // weights -> bf16
  k_f32_to_bf16<<<2048, blk, 0, stream>>>(Wq, Wb + 0 * WE2);
  k_f32_to_bf16<<<2048, blk, 0, stream>>>(Wk, Wb + 1 * WE2);
  k_f32_to_bf16<<<2048, blk, 0, stream>>>(Wv, Wb + 2 * WE2);
  k_f32_to_bf16<<<2048, blk, 0, stream>>>(Wo, Wb + 3 * WE2);

  // projections (M = B*N = 8192)
  k_f32_to_bf16<<<8192, blk, 0, stream>>>(query, X);
  k_gemm256<0><<<dim3(8, 32, 1), blk5, 0, stream>>>(X, EE, 0, Wb + 0 * WE2, EE, 0,
      Qb, EE, 0, EE, bq, nullptr, 0, 0.f);
  k_f32_to_bf16<<<8192, blk, 0, stream>>>(key_, X);
  k_gemm256<0><<<dim3(8, 32, 1), blk5, 0, stream>>>(X, EE, 0, Wb + 1 * WE2, EE, 0,
      Kb, EE, 0, EE, bk, nullptr, 0, 0.f);
  k_f32_to_bf16<<<8192, blk, 0, stream>>>(value, X);
  k_gemm256<0><<<dim3(8, 32, 1), blk5, 0, stream>>>(X, EE, 0, Wb + 2 * WE2, EE, 0,
      Vb, EE, 0, EE, bv, nullptr, 0, 0.f);

  // Vt[e,n] = V[n,e]
  k_transpose<<<dim3(32, 32, BB), blk, 0, stream>>>(Vb, X);

  // scores = Q K^T * scale + mask*(-1e9)   [fp32]
  k_gemm256<1><<<dim3(8, 8, BB), blk5, 0, stream>>>(Qb, EE, (long)NN * EE, Kb, EE, (long)NN * EE,
      SC, NN, (long)NN * NN, EE, nullptr, mask, (long)NN * NN, scale);

  // edge gate + softmax -> bf16 attn in place (row stride 2N bf16 elements)
  k_edge_softmax<<<BB * NN, blk, 0, stream>>>(SC, We, be);

  // O = attn * Vt^T  -> Vb region (bf16)
  k_gemm256<0><<<dim3(8, 8, BB), blk5, 0, stream>>>((const unsigned short*)SC, 2 * NN,
      (long)NN * 2 * NN, X, NN, (long)EE * NN, Vb, EE, (long)NN * EE, NN,
      nullptr, nullptr, 0, 0.f);

  // out = O * Wo^T + bo   [fp32]
  k_gemm256<2><<<dim3(8, 32, 1), blk5, 0, stream>>>(Vb, EE, 0, Wb + 3 * WE2, EE, 0,
      out, EE, 0, EE, bo, nullptr, 0, 0.f);
}